// Round 4
// baseline (575.529 us; speedup 1.0000x reference)
//
#include <hip/hip_runtime.h>
#include <stdint.h>

typedef unsigned short u16;
typedef __attribute__((ext_vector_type(4))) float f32x4;
typedef __attribute__((ext_vector_type(8))) short s16x8;

#define TB 4
#define TT 4096
#define TD 1024

__device__ __forceinline__ u16 f2bf(float f) {
  union { float f; uint32_t u; } v; v.f = f;
  return (u16)((v.u + 0x7FFFu + ((v.u >> 16) & 1u)) >> 16);
}

#define GLOAD_LDS16(g, l) __builtin_amdgcn_global_load_lds( \
    (const __attribute__((address_space(1))) void*)(g),      \
    (__attribute__((address_space(3))) void*)(l), 16, 0, 0)

#define MFMA16(a, b, c) __builtin_amdgcn_mfma_f32_16x16x32_bf16(a, b, c, 0, 0, 0)

// ---------------- cast fp32 -> bf16, vectorized ----------------
__global__ void cast_bf16(const float* __restrict__ in, u16* __restrict__ out, int n4) {
  int i = blockIdx.x * blockDim.x + threadIdx.x;
  int stride = gridDim.x * blockDim.x;
  for (; i < n4; i += stride) {
    float4 v = ((const float4*)in)[i];
    ushort4 o;
    o.x = f2bf(v.x); o.y = f2bf(v.y); o.z = f2bf(v.z); o.w = f2bf(v.w);
    ((ushort4*)out)[i] = o;
  }
}

// ---------------- GEMM 256x256 tile, 8 waves (2Mx4N), BK=64, 4-phase ----------------
// C[M,N] = A[M,K] * Bt[N,K]^T, bf16 in, fp32 acc.
// 4 phases per K-tile, 16 MFMA each (one C-quadrant x K=64). Staging of tile
// t+2 spread across phases at points where the target LDS region is fully
// read by ALL waves (B0@ph3, B1+A0@ph4 of iter t; A1@ph1 of iter t+1).
// vmcnt(8) once per K-tile (2 loads x 4 regions in flight), 0 only at tail.
// LDS swizzle: 16B-chunk ^= (row&7), pre-swizzled global source (rule #21).
// Per-z A offset is an explicit arg (z = batch or split-K slice).
template<bool OUT_BF16>
__global__ __launch_bounds__(512, 2)
void gemm256(const u16* __restrict__ Abase, const u16* __restrict__ Bt,
             void* __restrict__ C, int K, int lda, int ldb, int ldc, float scale,
             size_t oA0, size_t oA1, size_t oA2, size_t oA3,
             size_t sB, size_t sC) {
  // [slot(2)][op(2:A,B)][half(2)][row 128][chunk 8][8 u16] = 128 KiB
  __shared__ u16 ls[65536];
  const int tid  = threadIdx.x;
  const int lane = tid & 63;
  const int wid  = tid >> 6;   // 0..7
  const int wm   = wid >> 2;   // 0..1
  const int wn   = wid & 3;    // 0..3

  // bijective XCD-contiguous remap (nxy % 8 == 0 for all our grids)
  const int nxy = gridDim.x * gridDim.y;
  const int id  = blockIdx.y * gridDim.x + blockIdx.x;
  const int sid = (id & 7) * (nxy >> 3) + (id >> 3);
  const int bx  = sid % gridDim.x;
  const int by  = sid / gridDim.x;
  const int brow = by * 256;
  const int bcol = bx * 256;

  const int z = blockIdx.z;
  const size_t oA = (z == 0) ? oA0 : (z == 1) ? oA1 : (z == 2) ? oA2 : oA3;
  const u16* A = Abase + oA;
  Bt += (size_t)z * sB;

  const int lr = lane >> 3;        // row-within-8 of this lane's dest chunk
  const int lc = (lane & 7) ^ lr;  // swizzled source chunk

  // stage one region (op: 0=A,1=B; half: rows [0,128) or [128,256)) = 2 loads
  auto STAGE = [&](int slotB, int kt, int op, int half) {
    const size_t col = (size_t)kt * 64 + (size_t)lc * 8;
    const u16* g;
    int ld;
    if (op == 0) { g = A  + (size_t)(brow + half * 128) * lda; ld = lda; }
    else         { g = Bt + (size_t)(bcol + half * 128) * ldb; ld = ldb; }
#pragma unroll
    for (int i = 0; i < 2; ++i) {
      const int r = i * 64 + wid * 8 + lr;
      GLOAD_LDS16(g + (size_t)r * ld + col,
                  &ls[slotB + op * 16384 + half * 8192 + (i * 512 + wid * 64) * 8]);
    }
  };

  f32x4 acc[8][4];
#pragma unroll
  for (int m = 0; m < 8; ++m)
#pragma unroll
    for (int n = 0; n < 4; ++n) acc[m][n] = (f32x4){0.f, 0.f, 0.f, 0.f};

  const int nt = K >> 6;  // BK = 64

  // prologue: tile0 full (8 loads), tile1 B0,B1,A0 (6 loads); A1(1) at ph1(t=0)
  STAGE(0, 0, 0, 0); STAGE(0, 0, 0, 1); STAGE(0, 0, 1, 0); STAGE(0, 0, 1, 1);
  if (nt > 1) { STAGE(32768, 1, 1, 0); STAGE(32768, 1, 1, 1); STAGE(32768, 1, 0, 0); }

  // fragment read bases (u16 index, without slot / kk-chunk)
  const int r16 = lane & 15;
  const int k8  = lane >> 4;   // 0..3
  const int sw  = r16 & 7;
  const int c0  = ((k8)     ^ sw) * 8;   // kk0 chunk, swizzled
  const int c1  = ((4 | k8) ^ sw) * 8;   // kk1 chunk
  int aBase[8], bBase[4];
#pragma unroll
  for (int m = 0; m < 8; ++m) aBase[m] = wm * 8192 + (m * 16 + r16) * 64;
#pragma unroll
  for (int n = 0; n < 4; ++n) {
    int row = wn * 64 + n * 16 + r16;
    bBase[n] = 16384 + (row >> 7) * 8192 + (row & 127) * 64;
  }

  for (int t = 0; t < nt; ++t) {
    const int sb  = (t & 1) << 15;
    const int sbn = ((t + 1) & 1) << 15;

    s16x8 va0[4], va1[4];   // A frags kk0/kk1 for current m-half
    s16x8 vb[4][2];         // B frags [n][kk], live all 4 phases

    // ================= Phase 1: quadrant (m0..3, n0..1) =================
    if (t + 1 < nt) {
      STAGE(sbn, t + 1, 0, 1);                       // A1 of tile t+1
      asm volatile("s_waitcnt vmcnt(8)" ::: "memory");
    } else {
      asm volatile("s_waitcnt vmcnt(0)" ::: "memory");
    }
    asm volatile("s_barrier" ::: "memory");
#pragma unroll
    for (int m = 0; m < 4; ++m) {
      va0[m] = *(const s16x8*)&ls[sb + aBase[m] + c0];
      va1[m] = *(const s16x8*)&ls[sb + aBase[m] + c1];
    }
    vb[0][0] = *(const s16x8*)&ls[sb + bBase[0] + c0];
    vb[0][1] = *(const s16x8*)&ls[sb + bBase[0] + c1];
    vb[1][0] = *(const s16x8*)&ls[sb + bBase[1] + c0];
    vb[1][1] = *(const s16x8*)&ls[sb + bBase[1] + c1];
    asm volatile("s_waitcnt lgkmcnt(0)" ::: "memory");
    __builtin_amdgcn_sched_barrier(0);
    __builtin_amdgcn_s_setprio(1);
#pragma unroll
    for (int m = 0; m < 4; ++m) {
      acc[m][0] = MFMA16(va0[m], vb[0][0], acc[m][0]);
      acc[m][0] = MFMA16(va1[m], vb[0][1], acc[m][0]);
      acc[m][1] = MFMA16(va0[m], vb[1][0], acc[m][1]);
      acc[m][1] = MFMA16(va1[m], vb[1][1], acc[m][1]);
    }
    __builtin_amdgcn_s_setprio(0);
    asm volatile("s_barrier" ::: "memory");

    // ================= Phase 2: quadrant (m0..3, n2..3) =================
    vb[2][0] = *(const s16x8*)&ls[sb + bBase[2] + c0];
    vb[2][1] = *(const s16x8*)&ls[sb + bBase[2] + c1];
    vb[3][0] = *(const s16x8*)&ls[sb + bBase[3] + c0];
    vb[3][1] = *(const s16x8*)&ls[sb + bBase[3] + c1];
    asm volatile("s_waitcnt lgkmcnt(0)" ::: "memory");
    __builtin_amdgcn_sched_barrier(0);
    __builtin_amdgcn_s_setprio(1);
#pragma unroll
    for (int m = 0; m < 4; ++m) {
      acc[m][2] = MFMA16(va0[m], vb[2][0], acc[m][2]);
      acc[m][2] = MFMA16(va1[m], vb[2][1], acc[m][2]);
      acc[m][3] = MFMA16(va0[m], vb[3][0], acc[m][3]);
      acc[m][3] = MFMA16(va1[m], vb[3][1], acc[m][3]);
    }
    __builtin_amdgcn_s_setprio(0);
    asm volatile("s_barrier" ::: "memory");

    // ================= Phase 3: quadrant (m4..7, n0..1) =================
    if (t + 2 < nt) STAGE(sb, t + 2, 1, 0);          // B0 of tile t+2 (B fully read)
#pragma unroll
    for (int m = 0; m < 4; ++m) {
      va0[m] = *(const s16x8*)&ls[sb + aBase[m + 4] + c0];
      va1[m] = *(const s16x8*)&ls[sb + aBase[m + 4] + c1];
    }
    asm volatile("s_waitcnt lgkmcnt(0)" ::: "memory");
    __builtin_amdgcn_sched_barrier(0);
    __builtin_amdgcn_s_setprio(1);
#pragma unroll
    for (int m = 0; m < 4; ++m) {
      acc[m + 4][0] = MFMA16(va0[m], vb[0][0], acc[m + 4][0]);
      acc[m + 4][0] = MFMA16(va1[m], vb[0][1], acc[m + 4][0]);
      acc[m + 4][1] = MFMA16(va0[m], vb[1][0], acc[m + 4][1]);
      acc[m + 4][1] = MFMA16(va1[m], vb[1][1], acc[m + 4][1]);
    }
    __builtin_amdgcn_s_setprio(0);
    asm volatile("s_barrier" ::: "memory");

    // ================= Phase 4: quadrant (m4..7, n2..3) =================
    if (t + 2 < nt) { STAGE(sb, t + 2, 1, 1); STAGE(sb, t + 2, 0, 0); }  // B1, A0 (A fully read)
    __builtin_amdgcn_s_setprio(1);
#pragma unroll
    for (int m = 0; m < 4; ++m) {
      acc[m + 4][2] = MFMA16(va0[m], vb[2][0], acc[m + 4][2]);
      acc[m + 4][2] = MFMA16(va1[m], vb[2][1], acc[m + 4][2]);
      acc[m + 4][3] = MFMA16(va0[m], vb[3][0], acc[m + 4][3]);
      acc[m + 4][3] = MFMA16(va1[m], vb[3][1], acc[m + 4][3]);
    }
    __builtin_amdgcn_s_setprio(0);
    asm volatile("s_barrier" ::: "memory");
  }

  // epilogue: C/D layout col = lane&15, row = (lane>>4)*4 + reg
  const int c16 = lane & 15;
  const int rhi = lane >> 4;
#pragma unroll
  for (int m = 0; m < 8; ++m)
#pragma unroll
    for (int n = 0; n < 4; ++n)
#pragma unroll
      for (int r = 0; r < 4; ++r) {
        int grow = brow + wm * 128 + m * 16 + rhi * 4 + r;
        int gcol = bcol + wn * 64 + n * 16 + c16;
        float v = acc[m][n][r] * scale;
        if (OUT_BF16) ((u16*)C)[(size_t)z * sC + (size_t)grow * ldc + gcol] = f2bf(v);
        else          ((float*)C)[(size_t)z * sC + (size_t)grow * ldc + gcol] = v;
      }
}

// ---------------- transpose bf16: V[B][T][D] -> Vt[B][D][T], 64x64 tiles ----------------
__global__ __launch_bounds__(256)
void transpose_bf16(const u16* __restrict__ V, u16* __restrict__ Vt) {
  __shared__ u16 tile[64][65];
  int b  = blockIdx.z;
  int t0 = blockIdx.y * 64;
  int e0 = blockIdx.x * 64;
  const u16* Vb  = V  + (size_t)b * TT * TD;
  u16*       Vtb = Vt + (size_t)b * TT * TD;
  int r  = threadIdx.x >> 4;   // 0..15
  int c4 = threadIdx.x & 15;   // 0..15 -> cols c4*4..+3
#pragma unroll
  for (int i = 0; i < 4; ++i) {
    int row = r + i * 16;
    ushort4 v = *(const ushort4*)&Vb[(size_t)(t0 + row) * TD + e0 + c4 * 4];
    tile[row][c4 * 4 + 0] = v.x;
    tile[row][c4 * 4 + 1] = v.y;
    tile[row][c4 * 4 + 2] = v.z;
    tile[row][c4 * 4 + 3] = v.w;
  }
  __syncthreads();
#pragma unroll
  for (int i = 0; i < 4; ++i) {
    int e = r + i * 16;
    ushort4 o;
    o.x = tile[c4 * 4 + 0][e];
    o.y = tile[c4 * 4 + 1][e];
    o.z = tile[c4 * 4 + 2][e];
    o.w = tile[c4 * 4 + 3][e];
    *(ushort4*)&Vtb[(size_t)(e0 + e) * TT + t0 + c4 * 4] = o;
  }
}

// ---------------- row softmax: S[4096] fp32 -> P[4096] bf16 (1/l folded in) ----------------
__global__ __launch_bounds__(256)
void softmax_rows(const float* __restrict__ S, u16* __restrict__ P) {
  __shared__ float red_m[4];
  __shared__ float red_s[4];
  int row  = blockIdx.x;
  int tid  = threadIdx.x;
  int lane = tid & 63;
  int wid  = tid >> 6;
  const float4* Sr = (const float4*)(S + (size_t)row * 4096);

  float4 v[4];
  float m = -1e30f;
#pragma unroll
  for (int i = 0; i < 4; ++i) {
    v[i] = Sr[tid + i * 256];
    m = fmaxf(m, fmaxf(fmaxf(v[i].x, v[i].y), fmaxf(v[i].z, v[i].w)));
  }
#pragma unroll
  for (int off = 32; off >= 1; off >>= 1) m = fmaxf(m, __shfl_xor(m, off));
  if (lane == 0) red_m[wid] = m;
  __syncthreads();
  m = fmaxf(fmaxf(red_m[0], red_m[1]), fmaxf(red_m[2], red_m[3]));

  float e[16];
  float s = 0.f;
#pragma unroll
  for (int i = 0; i < 4; ++i) {
    e[i * 4 + 0] = __expf(v[i].x - m);
    e[i * 4 + 1] = __expf(v[i].y - m);
    e[i * 4 + 2] = __expf(v[i].z - m);
    e[i * 4 + 3] = __expf(v[i].w - m);
    s += e[i * 4 + 0] + e[i * 4 + 1] + e[i * 4 + 2] + e[i * 4 + 3];
  }
#pragma unroll
  for (int off = 32; off >= 1; off >>= 1) s += __shfl_xor(s, off);
  if (lane == 0) red_s[wid] = s;
  __syncthreads();
  s = red_s[0] + red_s[1] + red_s[2] + red_s[3];
  float inv = 1.0f / s;

  ushort4* Pr = (ushort4*)(P + (size_t)row * 4096);
#pragma unroll
  for (int i = 0; i < 4; ++i) {
    ushort4 o;
    o.x = f2bf(e[i * 4 + 0] * inv);
    o.y = f2bf(e[i * 4 + 1] * inv);
    o.z = f2bf(e[i * 4 + 2] * inv);
    o.w = f2bf(e[i * 4 + 3] * inv);
    Pr[tid + i * 256] = o;
  }
}

// ---------------- split-K reduction: out = sum of 4 partials ----------------
__global__ void reduce4(const float* __restrict__ p, float* __restrict__ out, int n4) {
  const size_t s = (size_t)TT * TD / 4;   // slice stride in float4 units
  int i = blockIdx.x * blockDim.x + threadIdx.x;
  int stride = gridDim.x * blockDim.x;
  for (; i < n4; i += stride) {
    float4 a = ((const float4*)p)[i];
    float4 b = ((const float4*)p)[i + s];
    float4 c = ((const float4*)p)[i + 2 * s];
    float4 d = ((const float4*)p)[i + 3 * s];
    float4 o;
    o.x = a.x + b.x + c.x + d.x;
    o.y = a.y + b.y + c.y + d.y;
    o.z = a.z + b.z + c.z + d.z;
    o.w = a.w + b.w + c.w + d.w;
    ((float4*)out)[i] = o;
  }
}

// ---------------- launch ----------------
extern "C" void kernel_launch(void* const* d_in, const int* in_sizes, int n_in,
                              void* d_out, int out_size, void* d_ws, size_t ws_size,
                              hipStream_t stream) {
  const float* x  = (const float*)d_in[0];
  const float* Wq = (const float*)d_in[1];
  const float* Wk = (const float*)d_in[2];
  const float* Wv = (const float*)d_in[3];
  float* out = (float*)d_out;

  const size_t MT = (size_t)TB * TT;      // 16384
  const size_t BE = (size_t)TT * TD;      // per-batch Q/K/V elements
  const size_t XE = MT * TD;              // 16,777,216
  const size_t PE = (size_t)TT * TT;      // per-batch scores (== XE)
  const size_t WE = (size_t)TD * TD;

  u16* xb    = (u16*)d_ws;                // later: P0
  u16* wqb   = xb + XE;
  u16* wkb   = wqb + WE;
  u16* wvb   = wkb + WE;
  u16* Q     = wvb + WE;                  // later: P3 (big path)
  u16* Kb    = Q + XE;
  u16* Vt    = Kb + XE;
  u16* Sbase = Vt + XE;                   // 2*PE u16 = PE fp32
  float* S   = (float*)Sbase;
  u16* V     = Sbase;                     // V overlays S (dead after transpose)
  u16* P1    = Sbase + 2 * PE;            // big path only
  u16* P2    = P1 + PE;

  const size_t need_big = ((size_t)(P2 + PE - xb)) * sizeof(u16);  // ~274.7 MB
  const bool big = ws_size >= need_big;

  // casts
  cast_bf16<<<2048, 256, 0, stream>>>(x,  xb,  (int)(XE / 4));
  cast_bf16<<<512,  256, 0, stream>>>(Wq, wqb, (int)(WE / 4));
  cast_bf16<<<512,  256, 0, stream>>>(Wk, wkb, (int)(WE / 4));
  cast_bf16<<<512,  256, 0, stream>>>(Wv, wvb, (int)(WE / 4));

  // projections: Q (scale 1/32), then K,V merged (z=2; V = Kb + 2*XE)
  dim3 blk(512);
  gemm256<true><<<dim3(TD / 256, MT / 256, 1), blk, 0, stream>>>(
      xb, wqb, Q, TD, TD, TD, TD, 0.03125f, 0, 0, 0, 0, 0, 0);
  gemm256<true><<<dim3(TD / 256, MT / 256, 2), blk, 0, stream>>>(
      xb, wkb, Kb, TD, TD, TD, TD, 1.0f, 0, 0, 0, 0, WE, 2 * XE);

  // V -> Vt
  transpose_bf16<<<dim3(TD / 64, TT / 64, TB), 256, 0, stream>>>(V, Vt);

  if (big) {
    // P0=xb, P1, P2, P3=Q (Q dead after QK^T(3))
    u16* Pp[4] = {xb, P1, P2, Q};
    for (int b = 0; b < TB; ++b) {
      gemm256<false><<<dim3(TT / 256, TT / 256, 1), blk, 0, stream>>>(
          Q + b * BE, Kb + b * BE, S, TD, TD, TD, TT, 1.0f, 0, 0, 0, 0, 0, 0);
      softmax_rows<<<TT, 256, 0, stream>>>(S, Pp[b]);
    }
    // batched PV: one dispatch, 256 blocks, per-z A offsets
    gemm256<false><<<dim3(TD / 256, TT / 256, TB), blk, 0, stream>>>(
        xb, Vt, out, TT, TT, TT, TD, 1.0f,
        0, (size_t)(P1 - xb), (size_t)(P2 - xb), (size_t)(Q - xb), BE, BE);
  } else {
    // fallback: per-batch, P reuses xb, split-K PV into S region + reduce
    u16* P = xb;
    float* part = S;
    for (int b = 0; b < TB; ++b) {
      gemm256<false><<<dim3(TT / 256, TT / 256, 1), blk, 0, stream>>>(
          Q + b * BE, Kb + b * BE, S, TD, TD, TD, TT, 1.0f, 0, 0, 0, 0, 0, 0);
      softmax_rows<<<TT, 256, 0, stream>>>(S, P);
      gemm256<false><<<dim3(TD / 256, TT / 256, 4), blk, 0, stream>>>(
          P, Vt + b * BE, part, TT / 4, TT, TT, TD, 1.0f,
          0, 1024, 2048, 3072, 1024, BE);
      reduce4<<<2048, 256, 0, stream>>>(part, out + b * BE, (int)(BE / 4));
    }
  }
}

// Round 5
// 559.394 us; speedup vs baseline: 1.0288x; 1.0288x over previous
//
#include <hip/hip_runtime.h>
#include <stdint.h>

typedef unsigned short u16;
typedef __attribute__((ext_vector_type(4))) float f32x4;
typedef __attribute__((ext_vector_type(8))) short s16x8;

#define TB 4
#define TT 4096
#define TD 1024

__device__ __forceinline__ u16 f2bf(float f) {
  union { float f; uint32_t u; } v; v.f = f;
  return (u16)((v.u + 0x7FFFu + ((v.u >> 16) & 1u)) >> 16);
}

#define GLOAD_LDS16(g, l) __builtin_amdgcn_global_load_lds( \
    (const __attribute__((address_space(1))) void*)(g),      \
    (__attribute__((address_space(3))) void*)(l), 16, 0, 0)

#define MFMA16(a, b, c) __builtin_amdgcn_mfma_f32_16x16x32_bf16(a, b, c, 0, 0, 0)

// ---------------- fused cast fp32 -> bf16 for x, Wq, Wk, Wv ----------------
// dst regions are contiguous in ws: [xb | wqb | wkb | wvb]
__global__ void cast_all(const float* __restrict__ x, const float* __restrict__ wq,
                         const float* __restrict__ wk, const float* __restrict__ wv,
                         u16* __restrict__ dst) {
  const int NX = 1 << 22;   // XE/4 float4s
  const int NW = 1 << 18;   // WE/4 float4s
  const int NT = NX + 3 * NW;
  int i = blockIdx.x * blockDim.x + threadIdx.x;
  int stride = gridDim.x * blockDim.x;
  for (; i < NT; i += stride) {
    float4 v;
    if (i < NX) {
      v = ((const float4*)x)[i];
    } else {
      int j = i - NX;
      int w = j >> 18;
      int off = j & (NW - 1);
      const float* p = (w == 0) ? wq : (w == 1) ? wk : wv;
      v = ((const float4*)p)[off];
    }
    ushort4 o;
    o.x = f2bf(v.x); o.y = f2bf(v.y); o.z = f2bf(v.z); o.w = f2bf(v.w);
    ((ushort4*)dst)[i] = o;
  }
}

// ---------------- GEMM 256x256 tile, 8 waves (2Mx4N), BK=64 ----------------
// C[M,N] = A[M,K] * Bt[N,K]^T, bf16 in, fp32 acc. R3-verified 2-phase loop:
// vmcnt(8) steady-state (0 only at tail), 2 barriers per K-tile, reads
// compiler-scheduled (no hard lgkm pins before cluster 1), setprio around
// MFMA clusters. LDS swizzle: 16B-chunk ^= (row&7) on the pre-swizzled
// global source (global_load_lds writes linearly) and on the reads.
// Per-z A offsets oA0..3 + B/C z-strides allow batching and split-K.
template<bool OUT_BF16>
__global__ __launch_bounds__(512)
void gemm256(const u16* __restrict__ Abase, const u16* __restrict__ Bt,
             void* __restrict__ C, int K, int lda, int ldb, int ldc, float scale,
             size_t oA0, size_t oA1, size_t oA2, size_t oA3,
             size_t sB, size_t sC) {
  // [slot(2)][op(2:A,B)][half(2)][row 128][chunk 8][8 u16] = 128 KiB
  __shared__ u16 ls[65536];
  const int tid  = threadIdx.x;
  const int lane = tid & 63;
  const int wid  = tid >> 6;   // 0..7
  const int wm   = wid >> 2;   // 0..1
  const int wn   = wid & 3;    // 0..3

  // bijective XCD-contiguous remap (nxy % 8 == 0 for all our grids)
  const int nxy = gridDim.x * gridDim.y;
  const int id  = blockIdx.y * gridDim.x + blockIdx.x;
  const int sid = (id & 7) * (nxy >> 3) + (id >> 3);
  const int bx  = sid % gridDim.x;
  const int by  = sid / gridDim.x;
  const int brow = by * 256;
  const int bcol = bx * 256;

  const int z = blockIdx.z;
  const size_t oA = (z == 0) ? oA0 : (z == 1) ? oA1 : (z == 2) ? oA2 : oA3;
  const u16* A = Abase + oA;
  Bt += (size_t)z * sB;

  const int lr = lane >> 3;        // row-within-8 of this lane's dest chunk
  const int lc = (lane & 7) ^ lr;  // swizzled source chunk

  f32x4 acc[8][4];
#pragma unroll
  for (int m = 0; m < 8; ++m)
#pragma unroll
    for (int n = 0; n < 4; ++n) acc[m][n] = (f32x4){0.f, 0.f, 0.f, 0.f};

  const int nt = K >> 6;  // BK = 64

  auto STAGE = [&](int slot, int kt) {
    const int sb = slot * 32768;
#pragma unroll
    for (int i = 0; i < 2; ++i) {
      const int r  = i * 64 + wid * 8 + lr;           // row within half (0..127)
      const int db = sb + (i * 512 + wid * 64) * 8;   // wave-uniform dest base
      const size_t col = (size_t)kt * 64 + (size_t)lc * 8;
      GLOAD_LDS16(A  + (size_t)(brow +       r) * lda + col, &ls[db]);
      GLOAD_LDS16(A  + (size_t)(brow + 128 + r) * lda + col, &ls[db + 8192]);
      GLOAD_LDS16(Bt + (size_t)(bcol +       r) * ldb + col, &ls[db + 16384]);
      GLOAD_LDS16(Bt + (size_t)(bcol + 128 + r) * ldb + col, &ls[db + 24576]);
    }
  };

  STAGE(0, 0);
  if (nt > 1) STAGE(1, 1);

  // fragment read bases (u16 index, without slot / kk-chunk)
  const int r16 = lane & 15;
  const int k8  = lane >> 4;   // 0..3
  const int sw  = r16 & 7;
  const int c0  = ((k8)     ^ sw) * 8;   // kk0 chunk, swizzled
  const int c1  = ((4 | k8) ^ sw) * 8;   // kk1 chunk
  int aBase[8], bBase[4];
#pragma unroll
  for (int m = 0; m < 8; ++m) aBase[m] = wm * 8192 + (m * 16 + r16) * 64;
#pragma unroll
  for (int n = 0; n < 4; ++n) {
    int row = wn * 64 + n * 16 + r16;
    bBase[n] = 16384 + (row >> 7) * 8192 + (row & 127) * 64;
  }

  for (int t = 0; t < nt; ++t) {
    const int sb = (t & 1) << 15;
    // tile t must be resident: 2-deep prefetch -> wait all but the newest 8
    if (t + 1 < nt) asm volatile("s_waitcnt vmcnt(8)" ::: "memory");
    else            asm volatile("s_waitcnt vmcnt(0)" ::: "memory");
    __builtin_amdgcn_s_barrier();
    __builtin_amdgcn_sched_barrier(0);

    s16x8 a0[8], b0[4];
#pragma unroll
    for (int m = 0; m < 8; ++m) a0[m] = *(const s16x8*)&ls[sb + aBase[m] + c0];
#pragma unroll
    for (int n = 0; n < 4; ++n) b0[n] = *(const s16x8*)&ls[sb + bBase[n] + c0];

    __builtin_amdgcn_s_setprio(1);
#pragma unroll
    for (int m = 0; m < 8; ++m)
#pragma unroll
      for (int n = 0; n < 4; ++n)
        acc[m][n] = MFMA16(a0[m], b0[n], acc[m][n]);
    __builtin_amdgcn_s_setprio(0);

    s16x8 a1[8], b1[4];
#pragma unroll
    for (int m = 0; m < 8; ++m) a1[m] = *(const s16x8*)&ls[sb + aBase[m] + c1];
#pragma unroll
    for (int n = 0; n < 4; ++n) b1[n] = *(const s16x8*)&ls[sb + bBase[n] + c1];

    // this wave's reads of slot (t&1) must complete before it is overwritten
    asm volatile("s_waitcnt lgkmcnt(0)" ::: "memory");
    __builtin_amdgcn_s_barrier();
    __builtin_amdgcn_sched_barrier(0);
    if (t + 2 < nt) STAGE(t & 1, t + 2);

    __builtin_amdgcn_s_setprio(1);
#pragma unroll
    for (int m = 0; m < 8; ++m)
#pragma unroll
      for (int n = 0; n < 4; ++n)
        acc[m][n] = MFMA16(a1[m], b1[n], acc[m][n]);
    __builtin_amdgcn_s_setprio(0);
  }

  // epilogue: C/D layout col = lane&15, row = (lane>>4)*4 + reg
  const int c16 = lane & 15;
  const int rhi = lane >> 4;
#pragma unroll
  for (int m = 0; m < 8; ++m)
#pragma unroll
    for (int n = 0; n < 4; ++n)
#pragma unroll
      for (int r = 0; r < 4; ++r) {
        int grow = brow + wm * 128 + m * 16 + rhi * 4 + r;
        int gcol = bcol + wn * 64 + n * 16 + c16;
        float v = acc[m][n][r] * scale;
        if (OUT_BF16) ((u16*)C)[(size_t)z * sC + (size_t)grow * ldc + gcol] = f2bf(v);
        else          ((float*)C)[(size_t)z * sC + (size_t)grow * ldc + gcol] = v;
      }
}

// ---------------- transpose bf16: V[B][T][D] -> Vt[B][D][T], 64x64 tiles ----------------
__global__ __launch_bounds__(256)
void transpose_bf16(const u16* __restrict__ V, u16* __restrict__ Vt) {
  __shared__ u16 tile[64][65];
  int b  = blockIdx.z;
  int t0 = blockIdx.y * 64;
  int e0 = blockIdx.x * 64;
  const u16* Vb  = V  + (size_t)b * TT * TD;
  u16*       Vtb = Vt + (size_t)b * TT * TD;
  int r  = threadIdx.x >> 4;   // 0..15
  int c4 = threadIdx.x & 15;   // 0..15 -> cols c4*4..+3
#pragma unroll
  for (int i = 0; i < 4; ++i) {
    int row = r + i * 16;
    ushort4 v = *(const ushort4*)&Vb[(size_t)(t0 + row) * TD + e0 + c4 * 4];
    tile[row][c4 * 4 + 0] = v.x;
    tile[row][c4 * 4 + 1] = v.y;
    tile[row][c4 * 4 + 2] = v.z;
    tile[row][c4 * 4 + 3] = v.w;
  }
  __syncthreads();
#pragma unroll
  for (int i = 0; i < 4; ++i) {
    int e = r + i * 16;
    ushort4 o;
    o.x = tile[c4 * 4 + 0][e];
    o.y = tile[c4 * 4 + 1][e];
    o.z = tile[c4 * 4 + 2][e];
    o.w = tile[c4 * 4 + 3][e];
    *(ushort4*)&Vtb[(size_t)(e0 + e) * TT + t0 + c4 * 4] = o;
  }
}

// ---------------- row softmax: S[4096] fp32 -> P[4096] bf16 (1/l folded in) ----------------
__global__ __launch_bounds__(256)
void softmax_rows(const float* __restrict__ S, u16* __restrict__ P) {
  __shared__ float red_m[4];
  __shared__ float red_s[4];
  int row  = blockIdx.x;
  int tid  = threadIdx.x;
  int lane = tid & 63;
  int wid  = tid >> 6;
  const float4* Sr = (const float4*)(S + (size_t)row * 4096);

  float4 v[4];
  float m = -1e30f;
#pragma unroll
  for (int i = 0; i < 4; ++i) {
    v[i] = Sr[tid + i * 256];
    m = fmaxf(m, fmaxf(fmaxf(v[i].x, v[i].y), fmaxf(v[i].z, v[i].w)));
  }
#pragma unroll
  for (int off = 32; off >= 1; off >>= 1) m = fmaxf(m, __shfl_xor(m, off));
  if (lane == 0) red_m[wid] = m;
  __syncthreads();
  m = fmaxf(fmaxf(red_m[0], red_m[1]), fmaxf(red_m[2], red_m[3]));

  float e[16];
  float s = 0.f;
#pragma unroll
  for (int i = 0; i < 4; ++i) {
    e[i * 4 + 0] = __expf(v[i].x - m);
    e[i * 4 + 1] = __expf(v[i].y - m);
    e[i * 4 + 2] = __expf(v[i].z - m);
    e[i * 4 + 3] = __expf(v[i].w - m);
    s += e[i * 4 + 0] + e[i * 4 + 1] + e[i * 4 + 2] + e[i * 4 + 3];
  }
#pragma unroll
  for (int off = 32; off >= 1; off >>= 1) s += __shfl_xor(s, off);
  if (lane == 0) red_s[wid] = s;
  __syncthreads();
  s = red_s[0] + red_s[1] + red_s[2] + red_s[3];
  float inv = 1.0f / s;

  ushort4* Pr = (ushort4*)(P + (size_t)row * 4096);
#pragma unroll
  for (int i = 0; i < 4; ++i) {
    ushort4 o;
    o.x = f2bf(e[i * 4 + 0] * inv);
    o.y = f2bf(e[i * 4 + 1] * inv);
    o.z = f2bf(e[i * 4 + 2] * inv);
    o.w = f2bf(e[i * 4 + 3] * inv);
    Pr[tid + i * 256] = o;
  }
}

// ---------------- split-K reduction: out = sum of 4 partials ----------------
__global__ void reduce4(const float* __restrict__ p, float* __restrict__ out, int n4) {
  const size_t s = (size_t)TT * TD / 4;   // slice stride in float4 units
  int i = blockIdx.x * blockDim.x + threadIdx.x;
  int stride = gridDim.x * blockDim.x;
  for (; i < n4; i += stride) {
    float4 a = ((const float4*)p)[i];
    float4 b = ((const float4*)p)[i + s];
    float4 c = ((const float4*)p)[i + 2 * s];
    float4 d = ((const float4*)p)[i + 3 * s];
    float4 o;
    o.x = a.x + b.x + c.x + d.x;
    o.y = a.y + b.y + c.y + d.y;
    o.z = a.z + b.z + c.z + d.z;
    o.w = a.w + b.w + c.w + d.w;
    ((float4*)out)[i] = o;
  }
}

// ---------------- launch ----------------
extern "C" void kernel_launch(void* const* d_in, const int* in_sizes, int n_in,
                              void* d_out, int out_size, void* d_ws, size_t ws_size,
                              hipStream_t stream) {
  const float* x  = (const float*)d_in[0];
  const float* Wq = (const float*)d_in[1];
  const float* Wk = (const float*)d_in[2];
  const float* Wv = (const float*)d_in[3];
  float* out = (float*)d_out;

  const size_t MT = (size_t)TB * TT;      // 16384
  const size_t BE = (size_t)TT * TD;      // per-batch Q/K/V elements
  const size_t XE = MT * TD;              // 16,777,216
  const size_t PE = (size_t)TT * TT;      // per-batch scores
  const size_t WE = (size_t)TD * TD;

  u16* xb    = (u16*)d_ws;                // later: P0
  u16* wqb   = xb + XE;
  u16* wkb   = wqb + WE;
  u16* wvb   = wkb + WE;
  u16* Q     = wvb + WE;                  // later: P3 (big path)
  u16* Kb    = Q + XE;
  u16* Vt    = Kb + XE;
  u16* Sbase = Vt + XE;                   // 2*PE u16 = PE fp32
  float* S   = (float*)Sbase;
  u16* V     = Sbase;                     // V overlays S (dead after transpose)
  u16* P1    = Sbase + 2 * PE;            // big path only
  u16* P2    = P1 + PE;

  const size_t need_big = ((size_t)(P2 + PE - xb)) * sizeof(u16);  // ~274.7 MB
  const bool big = ws_size >= need_big;

  // fused casts (dst regions contiguous: xb|wqb|wkb|wvb)
  cast_all<<<2048, 256, 0, stream>>>(x, Wq, Wk, Wv, xb);

  // projections: Q (scale 1/32), then K,V merged (z=2; V = Kb + 2*XE)
  dim3 blk(512);
  gemm256<true><<<dim3(TD / 256, MT / 256, 1), blk, 0, stream>>>(
      xb, wqb, Q, TD, TD, TD, TD, 0.03125f, 0, 0, 0, 0, 0, 0);
  gemm256<true><<<dim3(TD / 256, MT / 256, 2), blk, 0, stream>>>(
      xb, wkb, Kb, TD, TD, TD, TD, 1.0f, 0, 0, 0, 0, WE, 2 * XE);

  // V -> Vt
  transpose_bf16<<<dim3(TD / 64, TT / 64, TB), 256, 0, stream>>>(V, Vt);

  if (big) {
    // P0=xb, P1, P2, P3=Q (Q dead after QK^T(3))
    u16* Pp[4] = {xb, P1, P2, Q};
    for (int b = 0; b < TB; ++b) {
      gemm256<false><<<dim3(TT / 256, TT / 256, 1), blk, 0, stream>>>(
          Q + b * BE, Kb + b * BE, S, TD, TD, TD, TT, 1.0f, 0, 0, 0, 0, 0, 0);
      softmax_rows<<<TT, 256, 0, stream>>>(S, Pp[b]);
    }
    // batched PV: one dispatch, 1024-block-equivalent work in 256 blocks x z=4
    gemm256<false><<<dim3(TD / 256, TT / 256, TB), blk, 0, stream>>>(
        xb, Vt, out, TT, TT, TT, TD, 1.0f,
        0, (size_t)(P1 - xb), (size_t)(P2 - xb), (size_t)(Q - xb), BE, BE);
  } else {
    // fallback: per-batch, P reuses xb, split-K PV into S region + reduce
    u16* P = xb;
    float* part = S;
    for (int b = 0; b < TB; ++b) {
      gemm256<false><<<dim3(TT / 256, TT / 256, 1), blk, 0, stream>>>(
          Q + b * BE, Kb + b * BE, S, TD, TD, TD, TT, 1.0f, 0, 0, 0, 0, 0, 0);
      softmax_rows<<<TT, 256, 0, stream>>>(S, P);
      gemm256<false><<<dim3(TD / 256, TT / 256, 4), blk, 0, stream>>>(
          P, Vt + b * BE, part, TT / 4, TT, TT, TD, 1.0f,
          0, 1024, 2048, 3072, 1024, BE);
      reduce4<<<2048, 256, 0, stream>>>(part, out + b * BE, (int)(BE / 4));
    }
  }
}

// Round 6
// 463.061 us; speedup vs baseline: 1.2429x; 1.2080x over previous
//
#include <hip/hip_runtime.h>
#include <stdint.h>

typedef unsigned short u16;
typedef __attribute__((ext_vector_type(4))) float f32x4;
typedef __attribute__((ext_vector_type(8))) short s16x8;

#define TB 4
#define TT 4096
#define TD 1024

__device__ __forceinline__ u16 f2bf(float f) {
  union { float f; uint32_t u; } v; v.f = f;
  return (u16)((v.u + 0x7FFFu + ((v.u >> 16) & 1u)) >> 16);
}
__device__ __forceinline__ float bf2f(u16 h) {
  union { uint32_t u; float f; } v; v.u = ((uint32_t)h) << 16;
  return v.f;
}

#define GLOAD_LDS16(g, l) __builtin_amdgcn_global_load_lds( \
    (const __attribute__((address_space(1))) void*)(g),      \
    (__attribute__((address_space(3))) void*)(l), 16, 0, 0)

#define MFMA16(a, b, c) __builtin_amdgcn_mfma_f32_16x16x32_bf16(a, b, c, 0, 0, 0)
#define LDSV(o) (*(const s16x8*)&ls[(o)])

// ---------------- fused cast fp32 -> bf16 for x, Wq, Wk, Wv ----------------
__global__ void cast_all(const float* __restrict__ x, const float* __restrict__ wq,
                         const float* __restrict__ wk, const float* __restrict__ wv,
                         u16* __restrict__ dst) {
  const int NX = 1 << 22;   // XE/4 float4s
  const int NW = 1 << 18;   // WE/4 float4s
  const int NT = NX + 3 * NW;
  int i = blockIdx.x * blockDim.x + threadIdx.x;
  int stride = gridDim.x * blockDim.x;
  for (; i < NT; i += stride) {
    float4 v;
    if (i < NX) {
      v = ((const float4*)x)[i];
    } else {
      int j = i - NX;
      int w = j >> 18;
      int off = j & (NW - 1);
      const float* p = (w == 0) ? wq : (w == 1) ? wk : wv;
      v = ((const float4*)p)[off];
    }
    ushort4 o;
    o.x = f2bf(v.x); o.y = f2bf(v.y); o.z = f2bf(v.z); o.w = f2bf(v.w);
    ((ushort4*)dst)[i] = o;
  }
}

// ---------------- GEMM 256x256 tile, 8 waves (2Mx4N), BK=64, m201 8-phase ----------------
// C[M,N] = A[M,K] * Bt[N,K]^T, bf16 in, fp32 acc.
// Per K-tile: 4 phases, each { ds_read frags; stage 2 gloads; barrier;
// lgkmcnt(0); setprio(1) 16 MFMA setprio(0); barrier }. B frags hoisted to
// phase 0 (12 reads there, 4 in p1-3). Tile u's 8 gloads issue at
// (u-2).p1 (B rows 0,64), (u-2).p2 (B rows 128,192), (u-2).p3 (A rows 0,128),
// (u-1).p0 (A rows 64,192) -- each target region's last ds_read is >=1 barrier
// earlier. vmcnt(6) once per K-tile at p3 before the closing barrier
// (3 half-tiles = 6 loads in flight; 0 only at the tail).
// LDS swizzle: 16B-chunk ^= (row&7) on the pre-swizzled global source and reads.
template<bool OUT_BF16>
__global__ __launch_bounds__(512)
void gemm256(const u16* __restrict__ Abase, const u16* __restrict__ Bt,
             void* __restrict__ C, int K, int lda, int ldb, int ldc, float scale,
             size_t oA0, size_t oA1, size_t oA2, size_t oA3,
             size_t sB, size_t sC) {
  // [slot(2)][op(2:A,B)][256 rows][8 chunks][8 u16] = 128 KiB
  __shared__ u16 ls[65536];
  const int tid  = threadIdx.x;
  const int lane = tid & 63;
  const int wid  = tid >> 6;   // 0..7
  const int wm   = wid >> 2;   // 0..1
  const int wn   = wid & 3;    // 0..3

  // bijective XCD-contiguous remap (nxy % 8 == 0 for all our grids)
  const int nxy = gridDim.x * gridDim.y;
  const int id  = blockIdx.y * gridDim.x + blockIdx.x;
  const int sid = (id & 7) * (nxy >> 3) + (id >> 3);
  const int bx  = sid % gridDim.x;
  const int by  = sid / gridDim.x;
  const int brow = by * 256;
  const int bcol = bx * 256;

  const int z = blockIdx.z;
  const size_t oA = (z == 0) ? oA0 : (z == 1) ? oA1 : (z == 2) ? oA2 : oA3;
  const u16* A = Abase + oA;
  Bt += (size_t)z * sB;

  const int lr = lane >> 3;        // row-within-8 of this lane's dest chunk
  const int lc = (lane & 7) ^ lr;  // swizzled source chunk

  // stage one 64-row block (8 KB, 1 gload/thread)
  auto STAGE_BLK = [&](int slotB, int kt, int op, int r0) {
    const u16* g = op ? (Bt + (size_t)bcol * ldb) : (A + (size_t)brow * lda);
    const int ld = op ? ldb : lda;
    const int r  = r0 + wid * 8 + lr;
    GLOAD_LDS16(g + (size_t)r * ld + (size_t)kt * 64 + (size_t)lc * 8,
                &ls[slotB + op * 16384 + (r0 + wid * 8) * 64]);
  };

  f32x4 acc[8][4];
#pragma unroll
  for (int m = 0; m < 8; ++m)
#pragma unroll
    for (int n = 0; n < 4; ++n) acc[m][n] = (f32x4){0.f, 0.f, 0.f, 0.f};

  const int nt = K >> 6;  // BK = 64

  // prologue: tile0 complete; tile1 all but A rows 64,192 (those at t=0.p0)
  STAGE_BLK(0, 0, 0, 0);   STAGE_BLK(0, 0, 0, 64);
  STAGE_BLK(0, 0, 0, 128); STAGE_BLK(0, 0, 0, 192);
  STAGE_BLK(0, 0, 1, 0);   STAGE_BLK(0, 0, 1, 64);
  STAGE_BLK(0, 0, 1, 128); STAGE_BLK(0, 0, 1, 192);
  if (nt > 1) {
    STAGE_BLK(32768, 1, 1, 0);   STAGE_BLK(32768, 1, 1, 64);
    STAGE_BLK(32768, 1, 1, 128); STAGE_BLK(32768, 1, 1, 192);
    STAGE_BLK(32768, 1, 0, 0);   STAGE_BLK(32768, 1, 0, 128);
    asm volatile("s_waitcnt vmcnt(6)" ::: "memory");
  } else {
    asm volatile("s_waitcnt vmcnt(0)" ::: "memory");
  }
  __builtin_amdgcn_s_barrier();

  // fragment read bases (u16 index, without slot / kk-chunk)
  const int r16 = lane & 15;
  const int k8  = lane >> 4;             // 0..3
  const int sw  = r16 & 7;
  const int c0  = ((k8)     ^ sw) * 8;   // kk0 chunk, swizzled
  const int c1  = ((4 | k8) ^ sw) * 8;   // kk1 chunk
  int aBase[8], bBase[4];
#pragma unroll
  for (int m = 0; m < 8; ++m) aBase[m] = (wm * 128 + m * 16 + r16) * 64;
#pragma unroll
  for (int n = 0; n < 4; ++n) bBase[n] = 16384 + (wn * 64 + n * 16 + r16) * 64;

#define READ_A(P)                                                              \
  af[0][0] = LDSV(sb + aBase[2*(P)]   + c0); af[0][1] = LDSV(sb + aBase[2*(P)]   + c1); \
  af[1][0] = LDSV(sb + aBase[2*(P)+1] + c0); af[1][1] = LDSV(sb + aBase[2*(P)+1] + c1);

#define MIDSYNC()                                                              \
  __builtin_amdgcn_sched_barrier(0);                                           \
  __builtin_amdgcn_s_barrier();                                                \
  asm volatile("s_waitcnt lgkmcnt(0)" ::: "memory");                           \
  __builtin_amdgcn_sched_barrier(0);

#define PHASE_MFMA(P)                                                          \
  __builtin_amdgcn_s_setprio(1);                                               \
  _Pragma("unroll")                                                            \
  for (int mm = 0; mm < 2; ++mm)                                               \
    _Pragma("unroll")                                                          \
    for (int n = 0; n < 4; ++n) {                                              \
      acc[2*(P)+mm][n] = MFMA16(af[mm][0], bf[n][0], acc[2*(P)+mm][n]);        \
      acc[2*(P)+mm][n] = MFMA16(af[mm][1], bf[n][1], acc[2*(P)+mm][n]);        \
    }                                                                          \
  __builtin_amdgcn_s_setprio(0);

  for (int t = 0; t < nt; ++t) {
    const int sb  = (t & 1) << 15;
    const int sbn = sb ^ 32768;
    const bool pf1 = (t + 1 < nt);
    const bool pf2 = (t + 2 < nt);
    s16x8 bf[4][2], af[2][2];

    // ===== phase 0: m0,m1 x all n; reads all B; stage (t+1) A rows 64,192 =====
    READ_A(0);
#pragma unroll
    for (int n = 0; n < 4; ++n) {
      bf[n][0] = LDSV(sb + bBase[n] + c0);
      bf[n][1] = LDSV(sb + bBase[n] + c1);
    }
    if (pf1) { STAGE_BLK(sbn, t + 1, 0, 64); STAGE_BLK(sbn, t + 1, 0, 192); }
    MIDSYNC();
    PHASE_MFMA(0);
    __builtin_amdgcn_s_barrier();

    // ===== phase 1: m2,m3; stage (t+2) B rows 0,64 =====
    READ_A(1);
    if (pf2) { STAGE_BLK(sb, t + 2, 1, 0); STAGE_BLK(sb, t + 2, 1, 64); }
    MIDSYNC();
    PHASE_MFMA(1);
    __builtin_amdgcn_s_barrier();

    // ===== phase 2: m4,m5; stage (t+2) B rows 128,192 =====
    READ_A(2);
    if (pf2) { STAGE_BLK(sb, t + 2, 1, 128); STAGE_BLK(sb, t + 2, 1, 192); }
    MIDSYNC();
    PHASE_MFMA(2);
    __builtin_amdgcn_s_barrier();

    // ===== phase 3: m6,m7; stage (t+2) A rows 0,128; tile-boundary vmcnt =====
    READ_A(3);
    if (pf2) { STAGE_BLK(sb, t + 2, 0, 0); STAGE_BLK(sb, t + 2, 0, 128); }
    MIDSYNC();
    PHASE_MFMA(3);
    if (pf2) asm volatile("s_waitcnt vmcnt(6)" ::: "memory");
    else     asm volatile("s_waitcnt vmcnt(0)" ::: "memory");
    __builtin_amdgcn_sched_barrier(0);
    __builtin_amdgcn_s_barrier();
  }
#undef READ_A
#undef MIDSYNC
#undef PHASE_MFMA

  // epilogue: C/D layout col = lane&15, row = (lane>>4)*4 + reg
  const int c16 = lane & 15;
  const int rhi = lane >> 4;
#pragma unroll
  for (int m = 0; m < 8; ++m)
#pragma unroll
    for (int n = 0; n < 4; ++n)
#pragma unroll
      for (int r = 0; r < 4; ++r) {
        int grow = brow + wm * 128 + m * 16 + rhi * 4 + r;
        int gcol = bcol + wn * 64 + n * 16 + c16;
        float v = acc[m][n][r] * scale;
        if (OUT_BF16) ((u16*)C)[(size_t)z * sC + (size_t)grow * ldc + gcol] = f2bf(v);
        else          ((float*)C)[(size_t)z * sC + (size_t)grow * ldc + gcol] = v;
      }
}

// ---------------- transpose bf16: V[B][T][D] -> Vt[B][D][T], 64x64 tiles ----------------
__global__ __launch_bounds__(256)
void transpose_bf16(const u16* __restrict__ V, u16* __restrict__ Vt) {
  __shared__ u16 tile[64][65];
  int b  = blockIdx.z;
  int t0 = blockIdx.y * 64;
  int e0 = blockIdx.x * 64;
  const u16* Vb  = V  + (size_t)b * TT * TD;
  u16*       Vtb = Vt + (size_t)b * TT * TD;
  int r  = threadIdx.x >> 4;   // 0..15
  int c4 = threadIdx.x & 15;   // 0..15 -> cols c4*4..+3
#pragma unroll
  for (int i = 0; i < 4; ++i) {
    int row = r + i * 16;
    ushort4 v = *(const ushort4*)&Vb[(size_t)(t0 + row) * TD + e0 + c4 * 4];
    tile[row][c4 * 4 + 0] = v.x;
    tile[row][c4 * 4 + 1] = v.y;
    tile[row][c4 * 4 + 2] = v.z;
    tile[row][c4 * 4 + 3] = v.w;
  }
  __syncthreads();
#pragma unroll
  for (int i = 0; i < 4; ++i) {
    int e = r + i * 16;
    ushort4 o;
    o.x = tile[c4 * 4 + 0][e];
    o.y = tile[c4 * 4 + 1][e];
    o.z = tile[c4 * 4 + 2][e];
    o.w = tile[c4 * 4 + 3][e];
    *(ushort4*)&Vtb[(size_t)(e0 + e) * TT + t0 + c4 * 4] = o;
  }
}

// ---------------- row softmax: S[4096] bf16 -> P[4096] bf16 (1/l folded) ----------------
__global__ __launch_bounds__(256)
void softmax_bf16(const u16* __restrict__ S, u16* __restrict__ P) {
  __shared__ float red_m[4];
  __shared__ float red_s[4];
  int row  = blockIdx.x;
  int tid  = threadIdx.x;
  int lane = tid & 63;
  int wid  = tid >> 6;
  const s16x8* Sr = (const s16x8*)(S + (size_t)row * 4096);

  float v[16];
  float m = -1e30f;
#pragma unroll
  for (int i = 0; i < 2; ++i) {
    s16x8 u = Sr[tid + i * 256];
#pragma unroll
    for (int j = 0; j < 8; ++j) {
      v[i * 8 + j] = bf2f((u16)u[j]);
      m = fmaxf(m, v[i * 8 + j]);
    }
  }
#pragma unroll
  for (int off = 32; off >= 1; off >>= 1) m = fmaxf(m, __shfl_xor(m, off));
  if (lane == 0) red_m[wid] = m;
  __syncthreads();
  m = fmaxf(fmaxf(red_m[0], red_m[1]), fmaxf(red_m[2], red_m[3]));

  float s = 0.f;
#pragma unroll
  for (int j = 0; j < 16; ++j) { v[j] = __expf(v[j] - m); s += v[j]; }
#pragma unroll
  for (int off = 32; off >= 1; off >>= 1) s += __shfl_xor(s, off);
  if (lane == 0) red_s[wid] = s;
  __syncthreads();
  s = red_s[0] + red_s[1] + red_s[2] + red_s[3];
  float inv = 1.0f / s;

  s16x8* Pr = (s16x8*)(P + (size_t)row * 4096);
#pragma unroll
  for (int i = 0; i < 2; ++i) {
    s16x8 o;
#pragma unroll
    for (int j = 0; j < 8; ++j) o[j] = (short)f2bf(v[i * 8 + j] * inv);
    Pr[tid + i * 256] = o;
  }
}

// ---------------- launch ----------------
extern "C" void kernel_launch(void* const* d_in, const int* in_sizes, int n_in,
                              void* d_out, int out_size, void* d_ws, size_t ws_size,
                              hipStream_t stream) {
  const float* x  = (const float*)d_in[0];
  const float* Wq = (const float*)d_in[1];
  const float* Wk = (const float*)d_in[2];
  const float* Wv = (const float*)d_in[3];
  float* out = (float*)d_out;

  const size_t MT = (size_t)TB * TT;      // 16384
  const size_t BE = (size_t)TT * TD;      // per-batch Q/K/V elements
  const size_t XE = MT * TD;              // 16,777,216 (== TT*TT/... == PE)
  const size_t WE = (size_t)TD * TD;

  // 241.2 MB total -- identical footprint to the proven R1 layout.
  u16* xb   = (u16*)d_ws;     // XE ; later P0
  u16* wqb  = xb + XE;        // WE
  u16* wkb  = wqb + WE;       // WE
  u16* wvb  = wkb + WE;       // WE
  u16* Q    = wvb + WE;       // XE ; later P3 (after QK^T(3))
  u16* Kb   = Q + XE;         // XE
  u16* Vt   = Kb + XE;        // XE
  u16* PB   = Vt + XE;        // 2*XE ; V-initial in first XE; later P1, P2
  u16* tmpS = PB + 2 * XE;    // XE ; bf16 scores, reused per batch

  // fused casts (dst regions contiguous: xb|wqb|wkb|wvb)
  cast_all<<<2048, 256, 0, stream>>>(x, Wq, Wk, Wv, xb);

  // projections: Q (scale 1/32), then K,V merged (z=2; Kb + 2*XE == PB == V)
  dim3 blk(512);
  gemm256<true><<<dim3(TD / 256, MT / 256, 1), blk, 0, stream>>>(
      xb, wqb, Q, TD, TD, TD, TD, 0.03125f, 0, 0, 0, 0, 0, 0);
  gemm256<true><<<dim3(TD / 256, MT / 256, 2), blk, 0, stream>>>(
      xb, wkb, Kb, TD, TD, TD, TD, 1.0f, 0, 0, 0, 0, WE, 2 * XE);

  // V (in PB) -> Vt ; PB free afterwards
  transpose_bf16<<<dim3(TD / 64, TT / 64, TB), 256, 0, stream>>>(PB, Vt);

  // per-batch QK^T (bf16 scores) + softmax into P homes
  u16* Pp[4] = {xb, PB, PB + XE, Q};
  for (int b = 0; b < TB; ++b) {
    gemm256<true><<<dim3(TT / 256, TT / 256, 1), blk, 0, stream>>>(
        Q + b * BE, Kb + b * BE, tmpS, TD, TD, TD, TT, 1.0f, 0, 0, 0, 0, 0, 0);
    softmax_bf16<<<TT, 256, 0, stream>>>(tmpS, Pp[b]);
  }

  // batched PV: one dispatch, 256 blocks, per-z A offsets
  gemm256<false><<<dim3(TD / 256, TT / 256, TB), blk, 0, stream>>>(
      xb, Vt, out, TT, TT, TT, TD, 1.0f,
      0, (size_t)(PB - xb), (size_t)(PB + XE - xb), (size_t)(Q - xb), BE, BE);
}

// Round 7
// 438.797 us; speedup vs baseline: 1.3116x; 1.0553x over previous
//
#include <hip/hip_runtime.h>
#include <stdint.h>

typedef unsigned short u16;
typedef __attribute__((ext_vector_type(4))) float f32x4;
typedef __attribute__((ext_vector_type(8))) short s16x8;

#define TB 4
#define TT 4096
#define TD 1024

__device__ __forceinline__ u16 f2bf(float f) {
  union { float f; uint32_t u; } v; v.f = f;
  return (u16)((v.u + 0x7FFFu + ((v.u >> 16) & 1u)) >> 16);
}
__device__ __forceinline__ float bf2f(u16 h) {
  union { uint32_t u; float f; } v; v.u = ((uint32_t)h) << 16;
  return v.f;
}

#define GLOAD_LDS16(g, l) __builtin_amdgcn_global_load_lds( \
    (const __attribute__((address_space(1))) void*)(g),      \
    (__attribute__((address_space(3))) void*)(l), 16, 0, 0)

#define MFMA16(a, b, c) __builtin_amdgcn_mfma_f32_16x16x32_bf16(a, b, c, 0, 0, 0)
#define LDSV(o) (*(const s16x8*)&ls[(o)])

// ---------------- fused cast fp32 -> bf16 for x, Wq, Wk, Wv ----------------
__global__ void cast_all(const float* __restrict__ x, const float* __restrict__ wq,
                         const float* __restrict__ wk, const float* __restrict__ wv,
                         u16* __restrict__ dst) {
  const int NX = 1 << 22;   // XE/4 float4s
  const int NW = 1 << 18;   // WE/4 float4s
  const int NT = NX + 3 * NW;
  int i = blockIdx.x * blockDim.x + threadIdx.x;
  int stride = gridDim.x * blockDim.x;
  for (; i < NT; i += stride) {
    float4 v;
    if (i < NX) {
      v = ((const float4*)x)[i];
    } else {
      int j = i - NX;
      int w = j >> 18;
      int off = j & (NW - 1);
      const float* p = (w == 0) ? wq : (w == 1) ? wk : wv;
      v = ((const float4*)p)[off];
    }
    ushort4 o;
    o.x = f2bf(v.x); o.y = f2bf(v.y); o.z = f2bf(v.z); o.w = f2bf(v.w);
    ((ushort4*)dst)[i] = o;
  }
}

// ---------------- GEMM 256x256 tile, 8 waves (2Mx4N), BK=64, pipelined 4-phase ----------------
// C[M,N] = A[M,K] * Bt[N,K]^T, bf16 in, fp32 acc.
// Software-pipelined fragment reads: phase p issues the ds_reads consumed in
// phase p+1 (A pairs ping-pong between af_x/af_y); B[8] + A01 of tile t+1 are
// read at t.p3 AFTER the m67 cluster (old regs dead -> reuse). Compiler
// inserts all lgkmcnt (reads are C++-visible); manual sync is only:
// 1 s_barrier per phase, vmcnt(4) at p2-end (t+1 resident, t+2's 4 in
// flight), vmcnt(0) at tails. setprio(1) around each 16-MFMA cluster.
// LDS swizzle: 16B-chunk ^= (row&7), pre-swizzled global source (rule #21).
// Per-z A and C offsets; B has uniform z-stride sB. scale = z==0 ? s0 : s1.
template<bool OUT_BF16>
__global__ __launch_bounds__(512)
void gemm256(const u16* __restrict__ Abase, const u16* __restrict__ Bt,
             void* __restrict__ C, int K, int lda, int ldb, int ldc,
             float s0, float s1,
             size_t oA0, size_t oA1, size_t oA2, size_t oA3, size_t sB,
             size_t oC0, size_t oC1, size_t oC2, size_t oC3) {
  // [slot(2)][op(2:A,B)][256 rows][8 chunks][8 u16] = 128 KiB
  __shared__ u16 ls[65536];
  const int tid  = threadIdx.x;
  const int lane = tid & 63;
  const int wid  = tid >> 6;   // 0..7
  const int wm   = wid >> 2;   // 0..1
  const int wn   = wid & 3;    // 0..3

  // bijective XCD-contiguous remap (nxy % 8 == 0 for all our grids)
  const int nxy = gridDim.x * gridDim.y;
  const int id  = blockIdx.y * gridDim.x + blockIdx.x;
  const int sid = (id & 7) * (nxy >> 3) + (id >> 3);
  const int bx  = sid % gridDim.x;
  const int by  = sid / gridDim.x;
  const int brow = by * 256;
  const int bcol = bx * 256;

  const int z = blockIdx.z;
  const size_t oA = (z == 0) ? oA0 : (z == 1) ? oA1 : (z == 2) ? oA2 : oA3;
  const size_t oC = (z == 0) ? oC0 : (z == 1) ? oC1 : (z == 2) ? oC2 : oC3;
  const float scale = (z == 0) ? s0 : s1;
  const u16* A = Abase + oA;
  Bt += (size_t)z * sB;

  const int lr = lane >> 3;        // row-within-8 of this lane's dest chunk
  const int lc = (lane & 7) ^ lr;  // swizzled source chunk

  // stage one 64-row block (8 KB, 1 gload/thread)
  auto STAGE_BLK = [&](int slotB, int kt, int op, int r0) {
    const u16* g = op ? (Bt + (size_t)bcol * ldb) : (A + (size_t)brow * lda);
    const int ld = op ? ldb : lda;
    const int r  = r0 + wid * 8 + lr;
    GLOAD_LDS16(g + (size_t)r * ld + (size_t)kt * 64 + (size_t)lc * 8,
                &ls[slotB + op * 16384 + (r0 + wid * 8) * 64]);
  };

  f32x4 acc[8][4];
#pragma unroll
  for (int m = 0; m < 8; ++m)
#pragma unroll
    for (int n = 0; n < 4; ++n) acc[m][n] = (f32x4){0.f, 0.f, 0.f, 0.f};

  const int nt = K >> 6;  // BK = 64

  // prologue: tile0 complete (8); tile1 B0..B192, A0, A128 (6 newest)
  STAGE_BLK(0, 0, 0, 0);   STAGE_BLK(0, 0, 0, 64);
  STAGE_BLK(0, 0, 0, 128); STAGE_BLK(0, 0, 0, 192);
  STAGE_BLK(0, 0, 1, 0);   STAGE_BLK(0, 0, 1, 64);
  STAGE_BLK(0, 0, 1, 128); STAGE_BLK(0, 0, 1, 192);
  if (nt > 1) {
    STAGE_BLK(32768, 1, 1, 0);   STAGE_BLK(32768, 1, 1, 64);
    STAGE_BLK(32768, 1, 1, 128); STAGE_BLK(32768, 1, 1, 192);
    STAGE_BLK(32768, 1, 0, 0);   STAGE_BLK(32768, 1, 0, 128);
    asm volatile("s_waitcnt vmcnt(6)" ::: "memory");
  } else {
    asm volatile("s_waitcnt vmcnt(0)" ::: "memory");
  }
  __builtin_amdgcn_s_barrier();

  // fragment read bases (u16 index, without slot / kk-chunk)
  const int r16 = lane & 15;
  const int k8  = lane >> 4;             // 0..3
  const int sw  = r16 & 7;
  const int c0  = ((k8)     ^ sw) * 8;   // kk0 chunk, swizzled
  const int c1  = ((4 | k8) ^ sw) * 8;   // kk1 chunk
  int aBase[8], bBase[4];
#pragma unroll
  for (int m = 0; m < 8; ++m) aBase[m] = (wm * 128 + m * 16 + r16) * 64;
#pragma unroll
  for (int n = 0; n < 4; ++n) bBase[n] = 16384 + (wn * 64 + n * 16 + r16) * 64;

  s16x8 bf[4][2], af_x[2][2], af_y[2][2];

#define READ_APAIR(DST, SB, M0)                               \
  DST[0][0] = LDSV((SB) + aBase[M0] + c0);                    \
  DST[0][1] = LDSV((SB) + aBase[M0] + c1);                    \
  DST[1][0] = LDSV((SB) + aBase[(M0) + 1] + c0);              \
  DST[1][1] = LDSV((SB) + aBase[(M0) + 1] + c1);

#define READ_B(SB)                                            \
  _Pragma("unroll")                                           \
  for (int n = 0; n < 4; ++n) {                               \
    bf[n][0] = LDSV((SB) + bBase[n] + c0);                    \
    bf[n][1] = LDSV((SB) + bBase[n] + c1);                    \
  }

#define CLUSTER(MB, AF)                                                  \
  __builtin_amdgcn_s_setprio(1);                                         \
  _Pragma("unroll")                                                      \
  for (int mm = 0; mm < 2; ++mm)                                         \
    _Pragma("unroll")                                                    \
    for (int n = 0; n < 4; ++n) {                                        \
      acc[(MB) + mm][n] = MFMA16(AF[mm][0], bf[n][0], acc[(MB) + mm][n]); \
      acc[(MB) + mm][n] = MFMA16(AF[mm][1], bf[n][1], acc[(MB) + mm][n]); \
    }                                                                    \
  __builtin_amdgcn_s_setprio(0);

  // initial frags for tile 0 (the "p3 reads" of a virtual tile -1)
  READ_B(0);
  READ_APAIR(af_x, 0, 0);

  for (int t = 0; t < nt; ++t) {
    const int sb  = (t & 1) << 15;
    const int sbn = sb ^ 32768;
    const bool pf1 = (t + 1 < nt);
    const bool pf2 = (t + 2 < nt);

    // ===== p0: MFMA m01; read A23; stage (t+1) A64,A192 =====
    if (pf1) { STAGE_BLK(sbn, t + 1, 0, 64); STAGE_BLK(sbn, t + 1, 0, 192); }
    READ_APAIR(af_y, sb, 2);
    CLUSTER(0, af_x);
    __builtin_amdgcn_s_barrier();

    // ===== p1: MFMA m23; read A45; stage (t+2) B0,B64 =====
    if (pf2) { STAGE_BLK(sb, t + 2, 1, 0); STAGE_BLK(sb, t + 2, 1, 64); }
    READ_APAIR(af_x, sb, 4);
    CLUSTER(2, af_y);
    __builtin_amdgcn_s_barrier();

    // ===== p2: MFMA m45; read A67; stage (t+2) B128,B192; vmcnt =====
    if (pf2) { STAGE_BLK(sb, t + 2, 1, 128); STAGE_BLK(sb, t + 2, 1, 192); }
    READ_APAIR(af_y, sb, 6);
    CLUSTER(4, af_x);
    if (pf2) asm volatile("s_waitcnt vmcnt(4)" ::: "memory");
    else     asm volatile("s_waitcnt vmcnt(0)" ::: "memory");
    __builtin_amdgcn_s_barrier();

    // ===== p3: MFMA m67; stage (t+2) A0,A128; read (t+1) B[8] + A01 =====
    if (pf2) { STAGE_BLK(sb, t + 2, 0, 0); STAGE_BLK(sb, t + 2, 0, 128); }
    CLUSTER(6, af_y);
    if (pf1) { READ_B(sbn); READ_APAIR(af_x, sbn, 0); }
    __builtin_amdgcn_s_barrier();
  }
#undef READ_APAIR
#undef READ_B
#undef CLUSTER

  // epilogue: C/D layout col = lane&15, row = (lane>>4)*4 + reg
  const int c16 = lane & 15;
  const int rhi = lane >> 4;
#pragma unroll
  for (int m = 0; m < 8; ++m)
#pragma unroll
    for (int n = 0; n < 4; ++n)
#pragma unroll
      for (int r = 0; r < 4; ++r) {
        int grow = brow + wm * 128 + m * 16 + rhi * 4 + r;
        int gcol = bcol + wn * 64 + n * 16 + c16;
        float v = acc[m][n][r] * scale;
        if (OUT_BF16) ((u16*)C)[oC + (size_t)grow * ldc + gcol] = f2bf(v);
        else          ((float*)C)[oC + (size_t)grow * ldc + gcol] = v;
      }
}

// ---------------- transpose bf16: V[B][T][D] -> Vt[B][D][T], 64x64 tiles ----------------
__global__ __launch_bounds__(256)
void transpose_bf16(const u16* __restrict__ V, u16* __restrict__ Vt) {
  __shared__ u16 tile[64][65];
  int b  = blockIdx.z;
  int t0 = blockIdx.y * 64;
  int e0 = blockIdx.x * 64;
  const u16* Vb  = V  + (size_t)b * TT * TD;
  u16*       Vtb = Vt + (size_t)b * TT * TD;
  int r  = threadIdx.x >> 4;   // 0..15
  int c4 = threadIdx.x & 15;   // 0..15 -> cols c4*4..+3
#pragma unroll
  for (int i = 0; i < 4; ++i) {
    int row = r + i * 16;
    ushort4 v = *(const ushort4*)&Vb[(size_t)(t0 + row) * TD + e0 + c4 * 4];
    tile[row][c4 * 4 + 0] = v.x;
    tile[row][c4 * 4 + 1] = v.y;
    tile[row][c4 * 4 + 2] = v.z;
    tile[row][c4 * 4 + 3] = v.w;
  }
  __syncthreads();
#pragma unroll
  for (int i = 0; i < 4; ++i) {
    int e = r + i * 16;
    ushort4 o;
    o.x = tile[c4 * 4 + 0][e];
    o.y = tile[c4 * 4 + 1][e];
    o.z = tile[c4 * 4 + 2][e];
    o.w = tile[c4 * 4 + 3][e];
    *(ushort4*)&Vtb[(size_t)(e0 + e) * TT + t0 + c4 * 4] = o;
  }
}

// ---------------- in-place row softmax over 4 batch homes, bf16 ----------------
__global__ __launch_bounds__(256)
void softmax4(u16* __restrict__ p0, u16* __restrict__ p1,
              u16* __restrict__ p2, u16* __restrict__ p3) {
  __shared__ float red_m[4];
  __shared__ float red_s[4];
  const int bi = blockIdx.x >> 12;
  u16* base = (bi == 0) ? p0 : (bi == 1) ? p1 : (bi == 2) ? p2 : p3;
  const int row = blockIdx.x & 4095;
  int tid  = threadIdx.x;
  int lane = tid & 63;
  int wid  = tid >> 6;
  s16x8* Sr = (s16x8*)(base + (size_t)row * 4096);

  float v[16];
  float m = -1e30f;
#pragma unroll
  for (int i = 0; i < 2; ++i) {
    s16x8 u = Sr[tid + i * 256];
#pragma unroll
    for (int j = 0; j < 8; ++j) {
      v[i * 8 + j] = bf2f((u16)u[j]);
      m = fmaxf(m, v[i * 8 + j]);
    }
  }
#pragma unroll
  for (int off = 32; off >= 1; off >>= 1) m = fmaxf(m, __shfl_xor(m, off));
  if (lane == 0) red_m[wid] = m;
  __syncthreads();
  m = fmaxf(fmaxf(red_m[0], red_m[1]), fmaxf(red_m[2], red_m[3]));

  float s = 0.f;
#pragma unroll
  for (int j = 0; j < 16; ++j) { v[j] = __expf(v[j] - m); s += v[j]; }
#pragma unroll
  for (int off = 32; off >= 1; off >>= 1) s += __shfl_xor(s, off);
  if (lane == 0) red_s[wid] = s;
  __syncthreads();
  s = red_s[0] + red_s[1] + red_s[2] + red_s[3];
  float inv = 1.0f / s;

#pragma unroll
  for (int i = 0; i < 2; ++i) {
    s16x8 o;
#pragma unroll
    for (int j = 0; j < 8; ++j) o[j] = (short)f2bf(v[i * 8 + j] * inv);
    Sr[tid + i * 256] = o;
  }
}

// ---------------- launch ----------------
extern "C" void kernel_launch(void* const* d_in, const int* in_sizes, int n_in,
                              void* d_out, int out_size, void* d_ws, size_t ws_size,
                              hipStream_t stream) {
  const float* x  = (const float*)d_in[0];
  const float* Wq = (const float*)d_in[1];
  const float* Wk = (const float*)d_in[2];
  const float* Wv = (const float*)d_in[3];
  float* out = (float*)d_out;

  const size_t MT = (size_t)TB * TT;      // 16384
  const size_t BE = (size_t)TT * TD;      // per-batch Q/K/V elements
  const size_t XE = MT * TD;              // 16,777,216 (== one batch of S)
  const size_t WE = (size_t)TD * TD;

  // 241.2 MB total -- identical footprint to the proven R1/R6 layout.
  u16* xb   = (u16*)d_ws;     // XE ; S/P home 0
  u16* wqb  = xb + XE;        // 3*WE (wq|wk|wv contiguous)
  u16* Q    = wqb + 3 * WE;   // XE
  u16* Kb   = Q + XE;         // XE
  u16* Vt   = Kb + XE;        // XE
  u16* PB   = Vt + XE;        // 2*XE ; V initially in first XE; homes 1,2
  u16* tmpS = PB + 2 * XE;    // XE ; home 3

  // fused casts (dst regions contiguous: xb|wqb|wkb|wvb)
  cast_all<<<2048, 256, 0, stream>>>(x, Wq, Wk, Wv, xb);

  dim3 blk(512);
  // merged QKV projection: z -> {Q (scale 1/32), K, V(-> PB)}
  gemm256<true><<<dim3(TD / 256, MT / 256, 3), blk, 0, stream>>>(
      xb, wqb, Q, TD, TD, TD, TD, 0.03125f, 1.0f,
      0, 0, 0, 0, WE,
      0, XE, (size_t)(PB - Q), 0);

  // V (in PB) -> Vt ; PB free afterwards
  transpose_bf16<<<dim3(TD / 64, TT / 64, TB), 256, 0, stream>>>(PB, Vt);

  // batched QK^T: z = batch; bf16 scores into homes {xb, PB, PB+XE, tmpS}
  gemm256<true><<<dim3(TT / 256, TT / 256, TB), blk, 0, stream>>>(
      Q, Kb, xb, TD, TD, TD, TT, 1.0f, 1.0f,
      0, BE, 2 * BE, 3 * BE, BE,
      0, (size_t)(PB - xb), (size_t)(PB + XE - xb), (size_t)(tmpS - xb));

  // softmax, in place, all 16384 rows in one dispatch
  softmax4<<<dim3(TB * TT), 256, 0, stream>>>(xb, PB, PB + XE, tmpS);

  // batched PV: one dispatch, per-z A homes, fp32 out
  gemm256<false><<<dim3(TD / 256, TT / 256, TB), blk, 0, stream>>>(
      xb, Vt, out, TT, TT, TT, TD, 1.0f, 1.0f,
      0, (size_t)(PB - xb), (size_t)(PB + XE - xb), (size_t)(tmpS - xb), BE,
      0, BE, 2 * BE, 3 * BE);
}

// Round 8
// 432.313 us; speedup vs baseline: 1.3313x; 1.0150x over previous
//
#include <hip/hip_runtime.h>
#include <stdint.h>

typedef unsigned short u16;
typedef __attribute__((ext_vector_type(4))) float f32x4;
typedef __attribute__((ext_vector_type(8))) short s16x8;

#define TB 4
#define TT 4096
#define TD 1024

__device__ __forceinline__ u16 f2bf(float f) {
  union { float f; uint32_t u; } v; v.f = f;
  return (u16)((v.u + 0x7FFFu + ((v.u >> 16) & 1u)) >> 16);
}
__device__ __forceinline__ float bf2f(u16 h) {
  union { uint32_t u; float f; } v; v.u = ((uint32_t)h) << 16;
  return v.f;
}

#define GLOAD_LDS16(g, l) __builtin_amdgcn_global_load_lds( \
    (const __attribute__((address_space(1))) void*)(g),      \
    (__attribute__((address_space(3))) void*)(l), 16, 0, 0)

#define MFMA16(a, b, c) __builtin_amdgcn_mfma_f32_16x16x32_bf16(a, b, c, 0, 0, 0)
#define LDSV(o) (*(const s16x8*)&ls[(o)])

// ---------------- fused cast fp32 -> bf16 for x, Wq, Wk, Wv ----------------
__global__ void cast_all(const float* __restrict__ x, const float* __restrict__ wq,
                         const float* __restrict__ wk, const float* __restrict__ wv,
                         u16* __restrict__ dst) {
  const int NX = 1 << 22;   // XE/4 float4s
  const int NW = 1 << 18;   // WE/4 float4s
  const int NT = NX + 3 * NW;
  int i = blockIdx.x * blockDim.x + threadIdx.x;
  int stride = gridDim.x * blockDim.x;
  for (; i < NT; i += stride) {
    float4 v;
    if (i < NX) {
      v = ((const float4*)x)[i];
    } else {
      int j = i - NX;
      int w = j >> 18;
      int off = j & (NW - 1);
      const float* p = (w == 0) ? wq : (w == 1) ? wk : wv;
      v = ((const float4*)p)[off];
    }
    ushort4 o;
    o.x = f2bf(v.x); o.y = f2bf(v.y); o.z = f2bf(v.z); o.w = f2bf(v.w);
    ((ushort4*)dst)[i] = o;
  }
}

// ---------------- GEMM 256x256, 8 waves (2Mx4N), BK=64, m201 2-tile/8-phase ----------------
// C[M,N] = A[M,K] * Bt[N,K]^T, bf16 in, fp32 acc.
// Loop iter computes K-tiles t0=2i (slot0, phases 1-4) and t1=2i+1 (slot1,
// phases 5-8). Phase = one acc quadrant (m-half x n-half) x full K=64 =
// 16 MFMA. B frags (8) held in regs across a tile's 4 phases -> per-phase
// ds_reads: 12/4/8/0. Each phase: { ds_reads; stage 1 half-tile (2 gloads);
// sched_pin; s_barrier; [compiler lgkmcnt]; setprio1; 16 MFMA; setprio0;
// s_barrier }. Stage rotation (region >=1 barrier after its last reader):
// ph1,2 -> A(s1) tile t1 ; ph3,4 -> B(s0) t2 ; ph5,6 -> A(s0) t2 ;
// ph7,8 -> B(s1) t3.  vmcnt(4) ONLY at ph4/ph8 (drains everything needed by
// the next 4 phases, leaves the 2 newest half-tiles in flight); vmcnt(0)
// only at the tail. LDS swizzle: 16B-chunk ^= (row&7), pre-swizzled global
// source (rule #21). Per-z A/C offsets; B z-stride sB; scale z==0?s0:s1.
template<bool OUT_BF16>
__global__ __launch_bounds__(512)
void gemm256(const u16* __restrict__ Abase, const u16* __restrict__ Bt,
             void* __restrict__ C, int K, int lda, int ldb, int ldc,
             float s0, float s1,
             size_t oA0, size_t oA1, size_t oA2, size_t oA3, size_t sB,
             size_t oC0, size_t oC1, size_t oC2, size_t oC3) {
  // [slot(2)][op(2:A,B)][256 rows][8 chunks][8 u16] = 128 KiB
  __shared__ u16 ls[65536];
  const int tid  = threadIdx.x;
  const int lane = tid & 63;
  const int wid  = tid >> 6;   // 0..7
  const int wm   = wid >> 2;   // 0..1
  const int wn   = wid & 3;    // 0..3

  // bijective XCD-contiguous remap (nxy % 8 == 0 for all our grids)
  const int nxy = gridDim.x * gridDim.y;
  const int id  = blockIdx.y * gridDim.x + blockIdx.x;
  const int sid = (id & 7) * (nxy >> 3) + (id >> 3);
  const int bx  = sid % gridDim.x;
  const int by  = sid / gridDim.x;
  const int brow = by * 256;
  const int bcol = bx * 256;

  const int z = blockIdx.z;
  const size_t oA = (z == 0) ? oA0 : (z == 1) ? oA1 : (z == 2) ? oA2 : oA3;
  const size_t oC = (z == 0) ? oC0 : (z == 1) ? oC1 : (z == 2) ? oC2 : oC3;
  const float scale = (z == 0) ? s0 : s1;
  const u16* A = Abase + oA;
  Bt += (size_t)z * sB;

  const int lr = lane >> 3;        // row-within-8 of this lane's dest chunk
  const int lc = (lane & 7) ^ lr;  // swizzled source chunk

  // one 64-row block (8 KB, 1 gload/thread); half-tile = 2 blocks
  auto SBLK = [&](int slotB, int kt, int op, int r0) {
    const u16* g = op ? (Bt + (size_t)bcol * ldb) : (A + (size_t)brow * lda);
    const int ld = op ? ldb : lda;
    const int r  = r0 + wid * 8 + lr;
    GLOAD_LDS16(g + (size_t)r * ld + (size_t)kt * 64 + (size_t)lc * 8,
                &ls[slotB + op * 16384 + (r0 + wid * 8) * 64]);
  };
  auto SHALF = [&](int slotB, int kt, int op, int h) {
    SBLK(slotB, kt, op, h * 128);
    SBLK(slotB, kt, op, h * 128 + 64);
  };

  f32x4 acc[8][4];
#pragma unroll
  for (int m = 0; m < 8; ++m)
#pragma unroll
    for (int n = 0; n < 4; ++n) acc[m][n] = (f32x4){0.f, 0.f, 0.f, 0.f};

  const int nt = K >> 6;   // BK=64; nt is even (K = 1024 or 4096)
  const int NI = nt >> 1;

  // prologue: tile0 complete into slot0; tile1 B-halves into slot1 (A at ph1,2)
  SHALF(0, 0, 0, 0); SHALF(0, 0, 0, 1);
  SHALF(0, 0, 1, 0); SHALF(0, 0, 1, 1);
  SHALF(32768, 1, 1, 0); SHALF(32768, 1, 1, 1);
  asm volatile("s_waitcnt vmcnt(4)" ::: "memory");
  __builtin_amdgcn_s_barrier();

  // fragment read bases (u16 index, without slot / kk-chunk)
  const int r16 = lane & 15;
  const int k8  = lane >> 4;             // 0..3
  const int sw  = r16 & 7;
  const int c0  = ((k8)     ^ sw) * 8;   // kk0 chunk, swizzled
  const int c1  = ((4 | k8) ^ sw) * 8;   // kk1 chunk
  int aBase[8], bBase[4];
#pragma unroll
  for (int m = 0; m < 8; ++m) aBase[m] = (wm * 128 + m * 16 + r16) * 64;
#pragma unroll
  for (int n = 0; n < 4; ++n) bBase[n] = 16384 + (wn * 64 + n * 16 + r16) * 64;

  s16x8 af[4][2], bf[4][2];

#define READ_A4(SB, MH)                                                        \
  af[0][0] = LDSV((SB) + aBase[(MH)*4+0] + c0); af[0][1] = LDSV((SB) + aBase[(MH)*4+0] + c1); \
  af[1][0] = LDSV((SB) + aBase[(MH)*4+1] + c0); af[1][1] = LDSV((SB) + aBase[(MH)*4+1] + c1); \
  af[2][0] = LDSV((SB) + aBase[(MH)*4+2] + c0); af[2][1] = LDSV((SB) + aBase[(MH)*4+2] + c1); \
  af[3][0] = LDSV((SB) + aBase[(MH)*4+3] + c0); af[3][1] = LDSV((SB) + aBase[(MH)*4+3] + c1);

#define READ_B2(SB, N0)                                                        \
  bf[(N0)  ][0] = LDSV((SB) + bBase[(N0)  ] + c0); bf[(N0)  ][1] = LDSV((SB) + bBase[(N0)  ] + c1); \
  bf[(N0)+1][0] = LDSV((SB) + bBase[(N0)+1] + c0); bf[(N0)+1][1] = LDSV((SB) + bBase[(N0)+1] + c1);

#define CLUST(MH, NH)                                                          \
  __builtin_amdgcn_s_setprio(1);                                               \
  _Pragma("unroll")                                                            \
  for (int mm = 0; mm < 4; ++mm) {                                             \
    _Pragma("unroll")                                                          \
    for (int nn = 0; nn < 2; ++nn) {                                           \
      acc[(MH)*4+mm][(NH)*2+nn] =                                              \
          MFMA16(af[mm][0], bf[(NH)*2+nn][0], acc[(MH)*4+mm][(NH)*2+nn]);      \
      acc[(MH)*4+mm][(NH)*2+nn] =                                              \
          MFMA16(af[mm][1], bf[(NH)*2+nn][1], acc[(MH)*4+mm][(NH)*2+nn]);      \
    }                                                                          \
  }                                                                            \
  __builtin_amdgcn_s_setprio(0);

#define PIN() __builtin_amdgcn_sched_barrier(0)
#define BAR() __builtin_amdgcn_s_barrier()

  for (int i = 0; i < NI; ++i) {
    const int t1 = 2 * i + 1, t2 = 2 * i + 2, t3 = 2 * i + 3;
    const bool p2 = t2 < nt, p3 = t3 < nt;

    // ===== ph1: tile t0 quadrant (m-half0, n-half0); 12 reads =====
    READ_A4(0, 0); READ_B2(0, 0);
    SHALF(32768, t1, 0, 0);
    PIN(); BAR();
    CLUST(0, 0);
    BAR();

    // ===== ph2: (m0, n-half1); 4 reads =====
    READ_B2(0, 2);
    SHALF(32768, t1, 0, 1);
    PIN(); BAR();
    CLUST(0, 1);
    BAR();

    // ===== ph3: (m-half1, n0); 8 reads =====
    READ_A4(0, 1);
    if (p2) SHALF(0, t2, 1, 0);
    PIN(); BAR();
    CLUST(1, 0);
    BAR();

    // ===== ph4: (m1, n1); 0 reads; tile-boundary vmcnt =====
    if (p2) SHALF(0, t2, 1, 1);
    PIN(); BAR();
    CLUST(1, 1);
    if (p2) asm volatile("s_waitcnt vmcnt(4)" ::: "memory");
    else    asm volatile("s_waitcnt vmcnt(0)" ::: "memory");
    BAR();

    // ===== ph5: tile t1 (m0, n0); 12 reads =====
    READ_A4(32768, 0); READ_B2(32768, 0);
    if (p2) SHALF(0, t2, 0, 0);
    PIN(); BAR();
    CLUST(0, 0);
    BAR();

    // ===== ph6: (m0, n1); 4 reads =====
    READ_B2(32768, 2);
    if (p2) SHALF(0, t2, 0, 1);
    PIN(); BAR();
    CLUST(0, 1);
    BAR();

    // ===== ph7: (m1, n0); 8 reads =====
    READ_A4(32768, 1);
    if (p3) SHALF(32768, t3, 1, 0);
    PIN(); BAR();
    CLUST(1, 0);
    BAR();

    // ===== ph8: (m1, n1); 0 reads; tile-boundary vmcnt =====
    if (p3) SHALF(32768, t3, 1, 1);
    PIN(); BAR();
    CLUST(1, 1);
    if (i + 1 < NI) asm volatile("s_waitcnt vmcnt(4)" ::: "memory");
    BAR();
  }
#undef READ_A4
#undef READ_B2
#undef CLUST
#undef PIN
#undef BAR

  // epilogue: C/D layout col = lane&15, row = (lane>>4)*4 + reg
  const int c16 = lane & 15;
  const int rhi = lane >> 4;
#pragma unroll
  for (int m = 0; m < 8; ++m)
#pragma unroll
    for (int n = 0; n < 4; ++n)
#pragma unroll
      for (int r = 0; r < 4; ++r) {
        int grow = brow + wm * 128 + m * 16 + rhi * 4 + r;
        int gcol = bcol + wn * 64 + n * 16 + c16;
        float v = acc[m][n][r] * scale;
        if (OUT_BF16) ((u16*)C)[oC + (size_t)grow * ldc + gcol] = f2bf(v);
        else          ((float*)C)[oC + (size_t)grow * ldc + gcol] = v;
      }
}

// ---------------- transpose bf16: V[B][T][D] -> Vt[B][D][T], 64x64 tiles ----------------
__global__ __launch_bounds__(256)
void transpose_bf16(const u16* __restrict__ V, u16* __restrict__ Vt) {
  __shared__ u16 tile[64][65];
  int b  = blockIdx.z;
  int t0 = blockIdx.y * 64;
  int e0 = blockIdx.x * 64;
  const u16* Vb  = V  + (size_t)b * TT * TD;
  u16*       Vtb = Vt + (size_t)b * TT * TD;
  int r  = threadIdx.x >> 4;   // 0..15
  int c4 = threadIdx.x & 15;   // 0..15 -> cols c4*4..+3
#pragma unroll
  for (int i = 0; i < 4; ++i) {
    int row = r + i * 16;
    ushort4 v = *(const ushort4*)&Vb[(size_t)(t0 + row) * TD + e0 + c4 * 4];
    tile[row][c4 * 4 + 0] = v.x;
    tile[row][c4 * 4 + 1] = v.y;
    tile[row][c4 * 4 + 2] = v.z;
    tile[row][c4 * 4 + 3] = v.w;
  }
  __syncthreads();
#pragma unroll
  for (int i = 0; i < 4; ++i) {
    int e = r + i * 16;
    ushort4 o;
    o.x = tile[c4 * 4 + 0][e];
    o.y = tile[c4 * 4 + 1][e];
    o.z = tile[c4 * 4 + 2][e];
    o.w = tile[c4 * 4 + 3][e];
    *(ushort4*)&Vtb[(size_t)(e0 + e) * TT + t0 + c4 * 4] = o;
  }
}

// ---------------- in-place row softmax over 4 batch homes, bf16 ----------------
__global__ __launch_bounds__(256)
void softmax4(u16* __restrict__ p0, u16* __restrict__ p1,
              u16* __restrict__ p2, u16* __restrict__ p3) {
  __shared__ float red_m[4];
  __shared__ float red_s[4];
  const int bi = blockIdx.x >> 12;
  u16* base = (bi == 0) ? p0 : (bi == 1) ? p1 : (bi == 2) ? p2 : p3;
  const int row = blockIdx.x & 4095;
  int tid  = threadIdx.x;
  int lane = tid & 63;
  int wid  = tid >> 6;
  s16x8* Sr = (s16x8*)(base + (size_t)row * 4096);

  float v[16];
  float m = -1e30f;
#pragma unroll
  for (int i = 0; i < 2; ++i) {
    s16x8 u = Sr[tid + i * 256];
#pragma unroll
    for (int j = 0; j < 8; ++j) {
      v[i * 8 + j] = bf2f((u16)u[j]);
      m = fmaxf(m, v[i * 8 + j]);
    }
  }
#pragma unroll
  for (int off = 32; off >= 1; off >>= 1) m = fmaxf(m, __shfl_xor(m, off));
  if (lane == 0) red_m[wid] = m;
  __syncthreads();
  m = fmaxf(fmaxf(red_m[0], red_m[1]), fmaxf(red_m[2], red_m[3]));

  float s = 0.f;
#pragma unroll
  for (int j = 0; j < 16; ++j) { v[j] = __expf(v[j] - m); s += v[j]; }
#pragma unroll
  for (int off = 32; off >= 1; off >>= 1) s += __shfl_xor(s, off);
  if (lane == 0) red_s[wid] = s;
  __syncthreads();
  s = red_s[0] + red_s[1] + red_s[2] + red_s[3];
  float inv = 1.0f / s;

#pragma unroll
  for (int i = 0; i < 2; ++i) {
    s16x8 o;
#pragma unroll
    for (int j = 0; j < 8; ++j) o[j] = (short)f2bf(v[i * 8 + j] * inv);
    Sr[tid + i * 256] = o;
  }
}

// ---------------- launch ----------------
extern "C" void kernel_launch(void* const* d_in, const int* in_sizes, int n_in,
                              void* d_out, int out_size, void* d_ws, size_t ws_size,
                              hipStream_t stream) {
  const float* x  = (const float*)d_in[0];
  const float* Wq = (const float*)d_in[1];
  const float* Wk = (const float*)d_in[2];
  const float* Wv = (const float*)d_in[3];
  float* out = (float*)d_out;

  const size_t MT = (size_t)TB * TT;      // 16384
  const size_t BE = (size_t)TT * TD;      // per-batch Q/K/V elements
  const size_t XE = MT * TD;              // 16,777,216 (== one batch of S)
  const size_t WE = (size_t)TD * TD;

  // 241.2 MB total -- identical footprint to the proven R1/R6/R7 layout.
  u16* xb   = (u16*)d_ws;     // XE ; S/P home 0
  u16* wqb  = xb + XE;        // 3*WE (wq|wk|wv contiguous)
  u16* Q    = wqb + 3 * WE;   // XE
  u16* Kb   = Q + XE;         // XE
  u16* Vt   = Kb + XE;        // XE
  u16* PB   = Vt + XE;        // 2*XE ; V initially in first XE; homes 1,2
  u16* tmpS = PB + 2 * XE;    // XE ; home 3

  // fused casts (dst regions contiguous: xb|wqb|wkb|wvb)
  cast_all<<<2048, 256, 0, stream>>>(x, Wq, Wk, Wv, xb);

  dim3 blk(512);
  // merged QKV projection: z -> {Q (scale 1/32), K, V(-> PB)}
  gemm256<true><<<dim3(TD / 256, MT / 256, 3), blk, 0, stream>>>(
      xb, wqb, Q, TD, TD, TD, TD, 0.03125f, 1.0f,
      0, 0, 0, 0, WE,
      0, XE, (size_t)(PB - Q), 0);

  // V (in PB) -> Vt ; PB free afterwards
  transpose_bf16<<<dim3(TD / 64, TT / 64, TB), 256, 0, stream>>>(PB, Vt);

  // batched QK^T: z = batch; bf16 scores into homes {xb, PB, PB+XE, tmpS}
  gemm256<true><<<dim3(TT / 256, TT / 256, TB), blk, 0, stream>>>(
      Q, Kb, xb, TD, TD, TD, TT, 1.0f, 1.0f,
      0, BE, 2 * BE, 3 * BE, BE,
      0, (size_t)(PB - xb), (size_t)(PB + XE - xb), (size_t)(tmpS - xb));

  // softmax, in place, all 16384 rows in one dispatch
  softmax4<<<dim3(TB * TT), 256, 0, stream>>>(xb, PB, PB + XE, tmpS);

  // batched PV: one dispatch, per-z A homes, fp32 out
  gemm256<false><<<dim3(TD / 256, TT / 256, TB), blk, 0, stream>>>(
      xb, Vt, out, TT, TT, TT, TD, 1.0f, 1.0f,
      0, (size_t)(PB - xb), (size_t)(PB + XE - xb), (size_t)(tmpS - xb), BE,
      0, BE, 2 * BE, 3 * BE);
}